// Round 19
// baseline (93.275 us; speedup 1.0000x reference)
//
#include <hip/hip_runtime.h>
#include <hip/hip_bf16.h>

typedef __attribute__((ext_vector_type(8))) short bf16x8;
typedef __attribute__((ext_vector_type(4))) float f32x4;
typedef __attribute__((ext_vector_type(16))) float f32x16;
typedef __attribute__((ext_vector_type(4))) short s16x4;
typedef __attribute__((ext_vector_type(4))) int i32x4;

#define MFMA(a, b, c) __builtin_amdgcn_mfma_f32_16x16x32_bf16(a, b, c, 0, 0, 0)
#define MFMA32(a, b, c) __builtin_amdgcn_mfma_f32_32x32x16_bf16(a, b, c, 0, 0, 0)

#define SCALE_F 0.08838834764831845f  // (2*64)^-0.5
#define LOG2E_F 1.4426950408889634f
#define THR2 11.541560327111708f  // 8 * log2(e): defer-max bound, log2 domain
// Raw v_exp_f32 (llvm.amdgcn.exp2.f32): one instruction, no denormal fixup.
#define EXP2(x) __builtin_amdgcn_exp2f(x)

__device__ __forceinline__ short f2bf(float f) {
  __hip_bfloat16 h = __float2bfloat16(f);
  return *reinterpret_cast<short*>(&h);
}

__device__ __forceinline__ void gld_lds16(const void* g, void* s) {
  __builtin_amdgcn_global_load_lds(
      (const __attribute__((address_space(1))) void*)g,
      (__attribute__((address_space(3))) void*)s, 16, 0, 0);
}

// ---------------------------------------------------------------------------
// merged preprocessing: blocks 0..4095 cast x1/x2 fp32->bf16 (elementwise);
// blocks 4096..4543 transpose-cast the three weights via 64x64 LDS tiles.
// Q-columns of Wqkv are pre-scaled by SCALE*log2e (exp2-domain softmax).
__global__ __launch_bounds__(256) void preprocess(
    const float* __restrict__ x1, const float* __restrict__ x2,
    const float* __restrict__ Wq1, const float* __restrict__ Wq2,
    const float* __restrict__ Wo, short* __restrict__ xb1,
    short* __restrict__ xb2, short* __restrict__ W1t, short* __restrict__ W2t,
    short* __restrict__ Wot) {
  __shared__ float t[64][65];  // +1 pad: conflict-free column reads
  const int tid = threadIdx.x;
  int bid = blockIdx.x;
  if (bid < 4096) {
    // elementwise cast of x1 (blocks 0..2047) / x2 (2048..4095)
    int idx = (bid * 256 + tid) * 4;
    const float* src = x1;
    short* dst = xb1;
    if (idx >= 4096 * 512) { idx -= 4096 * 512; src = x2; dst = xb2; }
    float4 v = *(const float4*)&src[idx];
    s16x4 o;
    o.x = f2bf(v.x); o.y = f2bf(v.y); o.z = f2bf(v.z); o.w = f2bf(v.w);
    *(s16x4*)&dst[idx] = o;
    return;
  }
  bid -= 4096;
  const float* src;
  short* dst;
  int C, r0, c0;
  bool isq;
  if (bid < 384) {
    src = (bid < 192) ? Wq1 : Wq2;
    dst = (bid < 192) ? W1t : W2t;
    int tb = bid % 192;
    C = 1536; isq = true;
    r0 = (tb / 24) * 64; c0 = (tb % 24) * 64;
  } else {
    src = Wo; dst = Wot;
    int tb = bid - 384;
    C = 512; isq = false;
    r0 = (tb / 8) * 64; c0 = (tb % 8) * 64;
  }
  const int lr = tid >> 4, lc = (tid & 15) * 4;
#pragma unroll
  for (int i = 0; i < 4; ++i) {
    float4 v = *(const float4*)&src[(size_t)(r0 + lr + 16 * i) * C + c0 + lc];
    t[lr + 16 * i][lc + 0] = v.x;
    t[lr + 16 * i][lc + 1] = v.y;
    t[lr + 16 * i][lc + 2] = v.z;
    t[lr + 16 * i][lc + 3] = v.w;
  }
  __syncthreads();
  const int oc = tid >> 2, orr = (tid & 3) * 16;
  const float sc =
      (isq && (c0 + oc) < 512) ? SCALE_F * LOG2E_F : 1.0f;  // exp2 fold
  short* dbase = dst + (size_t)(c0 + oc) * 512 + r0 + orr;
#pragma unroll
  for (int jj = 0; jj < 4; ++jj) {
    s16x4 ov;
    ov.x = f2bf(t[orr + 4 * jj + 0][oc] * sc);
    ov.y = f2bf(t[orr + 4 * jj + 1][oc] * sc);
    ov.z = f2bf(t[orr + 4 * jj + 2][oc] * sc);
    ov.w = f2bf(t[orr + 4 * jj + 3][oc] * sc);
    *(s16x4*)&dbase[4 * jj] = ov;
  }
}

// ---------------------------------------------------------------------------
// Merged dual-stream QKV GEMM: C = x @ Wqkv for both streams in one launch.
// grid (32, 24): blockIdx.y < 12 -> stream 1, else stream 2.
__global__ __launch_bounds__(256) void gemm_qkv(
    const short* __restrict__ xb1, const short* __restrict__ xb2,
    const short* __restrict__ W1t, const short* __restrict__ W2t,
    short* __restrict__ QK1, short* __restrict__ QK2,
    short* __restrict__ Vt1, short* __restrict__ Vt2) {
  __shared__ short As[128 * 64];
  __shared__ short Bs[128 * 64];
  const int tid = threadIdx.x;
  const int w = tid >> 6, l = tid & 63;
  const int sid = blockIdx.y >= 12;
  const short* A = sid ? xb2 : xb1;
  const short* Bt = sid ? W2t : W1t;
  short* C0 = sid ? QK2 : QK1;
  short* C1 = sid ? Vt2 : Vt1;
  const int m0 = blockIdx.x * 128;
  const int n0 = (sid ? blockIdx.y - 12 : blockIdx.y) * 128;
  const int mi = (w >> 1) * 64, ni = (w & 1) * 64;
  const int lrow = l & 15, lk8 = (l >> 4) * 8;
  const int K = 512;

  f32x4 acc[4][4] = {};

  for (int k0 = 0; k0 < K; k0 += 64) {
    for (int g = 0; g < 4; ++g) {
      int c = g * 256 + w * 64 + l;
      int row = c >> 3, c8 = (c & 7) * 8;
      int ldsoff = (g * 256 + w * 64) * 8;
      gld_lds16(A + (size_t)(m0 + row) * K + k0 + c8, (void*)(As + ldsoff));
      gld_lds16(Bt + (size_t)(n0 + row) * K + k0 + c8, (void*)(Bs + ldsoff));
    }
    __syncthreads();
    __builtin_amdgcn_s_setprio(1);
    for (int kp = 0; kp < 2; ++kp) {
      bf16x8 af[4], bfr[4];
      for (int mf = 0; mf < 4; ++mf)
        af[mf] = *(const bf16x8*)&As[(mi + mf * 16 + lrow) * 64 + kp * 32 + lk8];
      for (int nf = 0; nf < 4; ++nf)
        bfr[nf] = *(const bf16x8*)&Bs[(ni + nf * 16 + lrow) * 64 + kp * 32 + lk8];
      for (int mf = 0; mf < 4; ++mf)
        for (int nf = 0; nf < 4; ++nf)
          acc[mf][nf] = MFMA(af[mf], bfr[nf], acc[mf][nf]);
    }
    __builtin_amdgcn_s_setprio(0);
    __syncthreads();
  }

  for (int mf = 0; mf < 4; ++mf)
    for (int nf = 0; nf < 4; ++nf) {
      int colb = n0 + ni + nf * 16 + lrow;
      int rowb = m0 + mi + mf * 16 + (l >> 4) * 4;
      if (colb < 1024) {
        for (int r = 0; r < 4; ++r)
          C0[(size_t)(rowb + r) * 1024 + colb] = f2bf(acc[mf][nf][r]);
      } else {
        int bb = rowb >> 11, n = rowb & 2047;
        int cv = colb - 1024, hh = cv >> 6, d = cv & 63;
        s16x4 ov;
        ov.x = f2bf(acc[mf][nf][0]);
        ov.y = f2bf(acc[mf][nf][1]);
        ov.z = f2bf(acc[mf][nf][2]);
        ov.w = f2bf(acc[mf][nf][3]);
        *(s16x4*)&C1[(((size_t)(bb * 8 + hh) * 64 + d) << 11) + n] = ov;
      }
    }
}

// ---------------------------------------------------------------------------
// Output-projection GEMM, 64x64 tile (1024 blocks -> 4+ blocks/CU):
// Cf[8192,512] = A[8192,512] @ Wot[512,512]^T + bias
__global__ __launch_bounds__(256) void gemm_out(const short* __restrict__ A,
                                                const short* __restrict__ Bt,
                                                float* __restrict__ Cf,
                                                const float* __restrict__ bias) {
  __shared__ short As[64 * 64];
  __shared__ short Bs[64 * 64];
  const int tid = threadIdx.x;
  const int w = tid >> 6, l = tid & 63;
  const int m0 = blockIdx.x * 64, n0 = blockIdx.y * 64;
  const int mi = (w >> 1) * 32, ni = (w & 1) * 32;
  const int lrow = l & 15, lk8 = (l >> 4) * 8;
  const int K = 512, N = 512;

  f32x4 acc[2][2] = {};

  for (int k0 = 0; k0 < K; k0 += 64) {
    for (int g = 0; g < 2; ++g) {
      int c = g * 256 + tid;
      int row = c >> 3, c8 = (c & 7) * 8;
      gld_lds16(A + (size_t)(m0 + row) * K + k0 + c8, (void*)(As + c * 8));
      gld_lds16(Bt + (size_t)(n0 + row) * K + k0 + c8, (void*)(Bs + c * 8));
    }
    __syncthreads();
    __builtin_amdgcn_s_setprio(1);
    for (int kp = 0; kp < 2; ++kp) {
      bf16x8 af[2], bfr[2];
      for (int mf = 0; mf < 2; ++mf)
        af[mf] = *(const bf16x8*)&As[(mi + mf * 16 + lrow) * 64 + kp * 32 + lk8];
      for (int nf = 0; nf < 2; ++nf)
        bfr[nf] = *(const bf16x8*)&Bs[(ni + nf * 16 + lrow) * 64 + kp * 32 + lk8];
      for (int mf = 0; mf < 2; ++mf)
        for (int nf = 0; nf < 2; ++nf)
          acc[mf][nf] = MFMA(af[mf], bfr[nf], acc[mf][nf]);
    }
    __builtin_amdgcn_s_setprio(0);
    __syncthreads();
  }

  for (int mf = 0; mf < 2; ++mf)
    for (int nf = 0; nf < 2; ++nf)
      for (int r = 0; r < 4; ++r) {
        int row = m0 + mi + mf * 16 + (l >> 4) * 4 + r;
        int col = n0 + ni + nf * 16 + lrow;
        Cf[(size_t)row * N + col] = acc[mf][nf][r] + bias[col];
      }
}

// ---------------------------------------------------------------------------
// Dual-stream flash attention, v9r4: R18 structure (XCD swizzle, raw exp2)
// + chain shortening: QK split into per-stream accumulator chains (depth
// 8->4 MFMA32), balanced-tree max (depth 15->4, v_max3-fusable), and
// balanced-tree sum for lrun (depth 16->5).
__global__ __launch_bounds__(256, 2) void attn_kernel(
    const short* __restrict__ QK1, const short* __restrict__ QK2,
    const short* __restrict__ Vt1, const short* __restrict__ Vt2,
    short* __restrict__ Ocat) {
  __shared__ short lds[32768];  // 64KB: K1[2][4096] K2 V1 V2 (shorts)
  short* K1s = lds;
  short* K2s = lds + 8192;
  short* V1s = lds + 16384;
  short* V2s = lds + 24576;

  const int tid = threadIdx.x;
  const int w = tid >> 6, l = tid & 63;
  const int wq = w & 1, wk = w >> 1;
  const int lq = l & 31, hi = l >> 5;
  // XCD swizzle (bijective): same-xcd blocks share 2 bh values
  const int flat = blockIdx.y * 32 + blockIdx.x;
  const int slot = flat >> 3;
  const int bh = ((flat & 7) << 1) + (slot >> 5);
  const int qb = slot & 31;
  const int b = bh >> 3, h = bh & 7;

  const short* Q1p = QK1 + (size_t)b * 2048 * 1024 + h * 64;
  const short* K1p = Q1p + 512;
  const short* Q2p = QK2 + (size_t)b * 2048 * 1024 + h * 64;
  const short* K2p = Q2p + 512;
  const short* V1p = Vt1 + (size_t)bh * 64 * 2048;
  const short* V2p = Vt2 + (size_t)bh * 64 * 2048;

  // Q fragments: lane holds Q[q=lq][d = 16*ck + 8*hi + j], j=0..8
  const int qrow = qb * 64 + wq * 32 + lq;
  bf16x8 q1f[4], q2f[4];
#pragma unroll
  for (int ck = 0; ck < 4; ++ck) {
    q1f[ck] = *(const bf16x8*)&Q1p[(size_t)qrow * 1024 + ck * 16 + hi * 8];
    q2f[ck] = *(const bf16x8*)&Q2p[(size_t)qrow * 1024 + ck * 16 + hi * 8];
  }

  // O^T accumulators: o*a = d 0..31 tile, o*b = d 32..63; col = q = lq
  f32x16 o1a = {}, o1b = {}, o2a = {}, o2b = {};
  float mrun = -1e30f, lrun = 0.f;

  auto stage = [&](int buf, int kt) {
    const int kv0 = kt * 64;
#pragma unroll
    for (int gg = 0; gg < 2; ++gg) {
      int cl = gg * 256 + tid;
      int row = cl >> 3;
      int lc = (cl & 7) ^ (row & 7);  // bank-conflict XOR swizzle (rule 21)
      int lr = row & 31;
      // pi-permuted K row within each 32-row half
      int krow = kv0 + ((row >> 5) << 5) + (((lr >> 3) & 1) << 4) +
                 (((lr >> 2) & 1) << 3) + (((lr >> 4) & 1) << 2) + (lr & 3);
      int doff = buf * 4096 + cl * 8;
      gld_lds16(K1p + (size_t)krow * 1024 + lc * 8, (void*)(K1s + doff));
      gld_lds16(K2p + (size_t)krow * 1024 + lc * 8, (void*)(K2s + doff));
      gld_lds16(V1p + (size_t)row * 2048 + kv0 + lc * 8, (void*)(V1s + doff));
      gld_lds16(V2p + (size_t)row * 2048 + kv0 + lc * 8, (void*)(V2s + doff));
    }
  };
  auto swo = [&](int row, int kc) { return row * 64 + ((kc ^ (row & 7)) * 8); };

  int cur = 0;
  stage(0, 0);

  for (int kt = 0; kt < 32; ++kt) {
    if (kt + 1 < 32) {
      stage(cur ^ 1, kt + 1);  // 8 loads stay in flight across the iter
      asm volatile("s_waitcnt vmcnt(8)" ::: "memory");  // tile t complete
    } else {
      asm volatile("s_waitcnt vmcnt(0)" ::: "memory");
    }
    __builtin_amdgcn_s_barrier();

    // S^T[32 kv][32 q] (log2 domain), per-stream accumulator chains
    const int krd = 32 * wk + lq;
    f32x16 sA = {}, sB = {};
    __builtin_amdgcn_s_setprio(1);
#pragma unroll
    for (int ck = 0; ck < 4; ++ck) {
      bf16x8 k1 = *(const bf16x8*)&K1s[cur * 4096 + swo(krd, 2 * ck + hi)];
      bf16x8 k2 = *(const bf16x8*)&K2s[cur * 4096 + swo(krd, 2 * ck + hi)];
      sA = MFMA32(k1, q1f[ck], sA);
      sB = MFMA32(k2, q2f[ck], sB);
    }
    __builtin_amdgcn_s_setprio(0);
    f32x16 s = sA + sB;  // combine streams (independent 4-deep chains)

    // online softmax: balanced-tree max (v_max3-fusable)
    float x0 = fmaxf(fmaxf(s[0], s[1]), s[2]);
    float x1 = fmaxf(fmaxf(s[3], s[4]), s[5]);
    float x2 = fmaxf(fmaxf(s[6], s[7]), s[8]);
    float x3 = fmaxf(fmaxf(s[9], s[10]), s[11]);
    float x4 = fmaxf(fmaxf(s[12], s[13]), s[14]);
    float mx = fmaxf(fmaxf(fmaxf(x0, x1), fmaxf(x2, x3)), fmaxf(x4, s[15]));
    if (!__all(mx - mrun <= THR2)) {  // defer-max: rarely fires
      float rm = fmaxf(mx, __shfl_xor(mx, 32));
      float newm = fmaxf(mrun, rm);
      float corr = EXP2(mrun - newm);
      mrun = newm;
      lrun *= corr;
#pragma unroll
      for (int i = 0; i < 16; ++i) {
        o1a[i] *= corr; o1b[i] *= corr; o2a[i] *= corr; o2b[i] *= corr;
      }
    }
    float p[16];
#pragma unroll
    for (int i = 0; i < 16; ++i) p[i] = EXP2(s[i] - mrun);
    // balanced-tree sum (depth 5 instead of 16-deep serial chain)
    {
      float s0 = (p[0] + p[1]) + (p[2] + p[3]);
      float s1 = (p[4] + p[5]) + (p[6] + p[7]);
      float s2 = (p[8] + p[9]) + (p[10] + p[11]);
      float s3 = (p[12] + p[13]) + (p[14] + p[15]);
      lrun += (s0 + s1) + (s2 + s3);
    }

    // P register-local repack: pb[c][j] = p[(j&3) + 4c + 8*(j>>2)]
    __hip_bfloat162 a0 = __float22bfloat162_rn(float2{p[0], p[1]});
    __hip_bfloat162 a1 = __float22bfloat162_rn(float2{p[2], p[3]});
    __hip_bfloat162 a2 = __float22bfloat162_rn(float2{p[8], p[9]});
    __hip_bfloat162 a3 = __float22bfloat162_rn(float2{p[10], p[11]});
    __hip_bfloat162 b0 = __float22bfloat162_rn(float2{p[4], p[5]});
    __hip_bfloat162 b1 = __float22bfloat162_rn(float2{p[6], p[7]});
    __hip_bfloat162 b2 = __float22bfloat162_rn(float2{p[12], p[13]});
    __hip_bfloat162 b3 = __float22bfloat162_rn(float2{p[14], p[15]});
    i32x4 w0 = {*(int*)&a0, *(int*)&a1, *(int*)&a2, *(int*)&a3};
    i32x4 w1 = {*(int*)&b0, *(int*)&b1, *(int*)&b2, *(int*)&b3};
    bf16x8 pb0 = *(bf16x8*)&w0, pb1 = *(bf16x8*)&w1;

    // PV: O^T += V^T P^T over this wave's kv-half
    __builtin_amdgcn_s_setprio(1);
#pragma unroll
    for (int c = 0; c < 2; ++c) {
      bf16x8 pb = c ? pb1 : pb0;
      int kcv = 4 * wk + 2 * c + hi;
      bf16x8 v1a = *(const bf16x8*)&V1s[cur * 4096 + swo(lq, kcv)];
      bf16x8 v1b = *(const bf16x8*)&V1s[cur * 4096 + swo(32 + lq, kcv)];
      bf16x8 v2a = *(const bf16x8*)&V2s[cur * 4096 + swo(lq, kcv)];
      bf16x8 v2b = *(const bf16x8*)&V2s[cur * 4096 + swo(32 + lq, kcv)];
      o1a = MFMA32(v1a, pb, o1a);
      o1b = MFMA32(v1b, pb, o1b);
      o2a = MFMA32(v2a, pb, o2a);
      o2b = MFMA32(v2b, pb, o2b);
    }
    __builtin_amdgcn_s_setprio(0);

    asm volatile("s_waitcnt lgkmcnt(0)" ::: "memory");
    __builtin_amdgcn_s_barrier();
    cur ^= 1;
  }

  // ---- cross-wk merge: exact combine of the two kv-half partials ----
  lrun += __shfl_xor(lrun, 32);  // per-q total for this wave's half
  float* cb = (float*)lds;
  float* rg = cb + wq * 4224;  // per-wq region: 4096 O + 64 m + 64 l floats
  if (wk == 1) {
#pragma unroll
    for (int i = 0; i < 16; ++i) {
      rg[i * 64 + l] = o1a[i];
      rg[(16 + i) * 64 + l] = o1b[i];
      rg[(32 + i) * 64 + l] = o2a[i];
      rg[(48 + i) * 64 + l] = o2b[i];
    }
    rg[4096 + l] = mrun;
    rg[4160 + l] = lrun;
  }
  __syncthreads();
  if (wk == 0) {
    float m1 = rg[4096 + l], l1 = rg[4160 + l];
    float mstar = fmaxf(mrun, m1);
    float e0 = EXP2(mrun - mstar), e1 = EXP2(m1 - mstar);
    float inv = 1.0f / (lrun * e0 + l1 * e1);
    float av0 = e0 * inv, av1 = e1 * inv;
#pragma unroll
    for (int i = 0; i < 16; ++i) {
      o1a[i] = o1a[i] * av0 + rg[i * 64 + l] * av1;
      o1b[i] = o1b[i] * av0 + rg[(16 + i) * 64 + l] * av1;
      o2a[i] = o2a[i] * av0 + rg[(32 + i) * 64 + l] * av1;
      o2b[i] = o2b[i] * av0 + rg[(48 + i) * 64 + l] * av1;
    }
    // write: lane's d rows = 8*rq + 4*hi + e (+32 for *b tiles), q = lq
    const size_t base1 = ((size_t)b * 4096 + qrow) * 512 + h * 64;
    const size_t base2 = base1 + (size_t)2048 * 512;
#pragma unroll
    for (int rq = 0; rq < 4; ++rq) {
      int d0 = 8 * rq + 4 * hi;
      s16x4 ov;
      ov.x = f2bf(o1a[rq * 4 + 0]); ov.y = f2bf(o1a[rq * 4 + 1]);
      ov.z = f2bf(o1a[rq * 4 + 2]); ov.w = f2bf(o1a[rq * 4 + 3]);
      *(s16x4*)&Ocat[base1 + d0] = ov;
      ov.x = f2bf(o1b[rq * 4 + 0]); ov.y = f2bf(o1b[rq * 4 + 1]);
      ov.z = f2bf(o1b[rq * 4 + 2]); ov.w = f2bf(o1b[rq * 4 + 3]);
      *(s16x4*)&Ocat[base1 + 32 + d0] = ov;
      ov.x = f2bf(o2a[rq * 4 + 0]); ov.y = f2bf(o2a[rq * 4 + 1]);
      ov.z = f2bf(o2a[rq * 4 + 2]); ov.w = f2bf(o2a[rq * 4 + 3]);
      *(s16x4*)&Ocat[base2 + d0] = ov;
      ov.x = f2bf(o2b[rq * 4 + 0]); ov.y = f2bf(o2b[rq * 4 + 1]);
      ov.z = f2bf(o2b[rq * 4 + 2]); ov.w = f2bf(o2b[rq * 4 + 3]);
      *(s16x4*)&Ocat[base2 + 32 + d0] = ov;
    }
  }
}

// ---------------------------------------------------------------------------
extern "C" void kernel_launch(void* const* d_in, const int* in_sizes, int n_in,
                              void* d_out, int out_size, void* d_ws,
                              size_t ws_size, hipStream_t stream) {
  const float* x1 = (const float*)d_in[0];
  const float* x2 = (const float*)d_in[1];
  const float* Wq1 = (const float*)d_in[2];
  const float* Wq2 = (const float*)d_in[3];
  const float* Wo = (const float*)d_in[4];
  const float* bo = (const float*)d_in[5];
  float* out = (float*)d_out;

  // workspace layout (bf16 elements); total ~45.6 MB
  short* p = (short*)d_ws;
  short* xb1 = p;  p += (size_t)4096 * 512;
  short* xb2 = p;  p += (size_t)4096 * 512;
  short* W1t = p;  p += (size_t)1536 * 512;
  short* W2t = p;  p += (size_t)1536 * 512;
  short* Wot = p;  p += (size_t)512 * 512;
  short* QK1 = p;  p += (size_t)4096 * 1024;
  short* QK2 = p;  p += (size_t)4096 * 1024;
  short* Vt1 = p;  p += (size_t)2 * 8 * 64 * 2048;
  short* Vt2 = p;  p += (size_t)2 * 8 * 64 * 2048;
  short* Ocat = p; p += (size_t)8192 * 512;

  preprocess<<<4544, 256, 0, stream>>>(x1, x2, Wq1, Wq2, Wo, xb1, xb2, W1t,
                                       W2t, Wot);

  gemm_qkv<<<dim3(32, 24), 256, 0, stream>>>(xb1, xb2, W1t, W2t, QK1, QK2,
                                             Vt1, Vt2);

  attn_kernel<<<dim3(32, 16), 256, 0, stream>>>(QK1, QK2, Vt1, Vt2, Ocat);

  gemm_out<<<dim3(128, 8), 256, 0, stream>>>(Ocat, Wot, out, bo);
}

// Round 20
// 92.627 us; speedup vs baseline: 1.0070x; 1.0070x over previous
//
#include <hip/hip_runtime.h>
#include <hip/hip_bf16.h>

typedef __attribute__((ext_vector_type(8))) short bf16x8;
typedef __attribute__((ext_vector_type(4))) float f32x4;
typedef __attribute__((ext_vector_type(16))) float f32x16;
typedef __attribute__((ext_vector_type(4))) short s16x4;
typedef __attribute__((ext_vector_type(4))) int i32x4;

#define MFMA(a, b, c) __builtin_amdgcn_mfma_f32_16x16x32_bf16(a, b, c, 0, 0, 0)
#define MFMA32(a, b, c) __builtin_amdgcn_mfma_f32_32x32x16_bf16(a, b, c, 0, 0, 0)

#define SCALE_F 0.08838834764831845f  // (2*64)^-0.5
#define LOG2E_F 1.4426950408889634f
#define THR2 11.541560327111708f  // 8 * log2(e): defer-max bound, log2 domain
// Raw v_exp_f32 (llvm.amdgcn.exp2.f32): one instruction, no denormal fixup.
#define EXP2(x) __builtin_amdgcn_exp2f(x)

__device__ __forceinline__ short f2bf(float f) {
  __hip_bfloat16 h = __float2bfloat16(f);
  return *reinterpret_cast<short*>(&h);
}

__device__ __forceinline__ void gld_lds16(const void* g, void* s) {
  __builtin_amdgcn_global_load_lds(
      (const __attribute__((address_space(1))) void*)g,
      (__attribute__((address_space(3))) void*)s, 16, 0, 0);
}

// ---------------------------------------------------------------------------
// merged preprocessing: blocks 0..4095 cast x1/x2 fp32->bf16 (elementwise);
// blocks 4096..4543 transpose-cast the three weights via 64x64 LDS tiles.
// Q-columns of Wqkv are pre-scaled by SCALE*log2e (exp2-domain softmax).
__global__ __launch_bounds__(256) void preprocess(
    const float* __restrict__ x1, const float* __restrict__ x2,
    const float* __restrict__ Wq1, const float* __restrict__ Wq2,
    const float* __restrict__ Wo, short* __restrict__ xb1,
    short* __restrict__ xb2, short* __restrict__ W1t, short* __restrict__ W2t,
    short* __restrict__ Wot) {
  __shared__ float t[64][65];  // +1 pad: conflict-free column reads
  const int tid = threadIdx.x;
  int bid = blockIdx.x;
  if (bid < 4096) {
    // elementwise cast of x1 (blocks 0..2047) / x2 (2048..4095)
    int idx = (bid * 256 + tid) * 4;
    const float* src = x1;
    short* dst = xb1;
    if (idx >= 4096 * 512) { idx -= 4096 * 512; src = x2; dst = xb2; }
    float4 v = *(const float4*)&src[idx];
    s16x4 o;
    o.x = f2bf(v.x); o.y = f2bf(v.y); o.z = f2bf(v.z); o.w = f2bf(v.w);
    *(s16x4*)&dst[idx] = o;
    return;
  }
  bid -= 4096;
  const float* src;
  short* dst;
  int C, r0, c0;
  bool isq;
  if (bid < 384) {
    src = (bid < 192) ? Wq1 : Wq2;
    dst = (bid < 192) ? W1t : W2t;
    int tb = bid % 192;
    C = 1536; isq = true;
    r0 = (tb / 24) * 64; c0 = (tb % 24) * 64;
  } else {
    src = Wo; dst = Wot;
    int tb = bid - 384;
    C = 512; isq = false;
    r0 = (tb / 8) * 64; c0 = (tb % 8) * 64;
  }
  const int lr = tid >> 4, lc = (tid & 15) * 4;
#pragma unroll
  for (int i = 0; i < 4; ++i) {
    float4 v = *(const float4*)&src[(size_t)(r0 + lr + 16 * i) * C + c0 + lc];
    t[lr + 16 * i][lc + 0] = v.x;
    t[lr + 16 * i][lc + 1] = v.y;
    t[lr + 16 * i][lc + 2] = v.z;
    t[lr + 16 * i][lc + 3] = v.w;
  }
  __syncthreads();
  const int oc = tid >> 2, orr = (tid & 3) * 16;
  const float sc =
      (isq && (c0 + oc) < 512) ? SCALE_F * LOG2E_F : 1.0f;  // exp2 fold
  short* dbase = dst + (size_t)(c0 + oc) * 512 + r0 + orr;
#pragma unroll
  for (int jj = 0; jj < 4; ++jj) {
    s16x4 ov;
    ov.x = f2bf(t[orr + 4 * jj + 0][oc] * sc);
    ov.y = f2bf(t[orr + 4 * jj + 1][oc] * sc);
    ov.z = f2bf(t[orr + 4 * jj + 2][oc] * sc);
    ov.w = f2bf(t[orr + 4 * jj + 3][oc] * sc);
    *(s16x4*)&dbase[4 * jj] = ov;
  }
}

// ---------------------------------------------------------------------------
// Merged dual-stream QKV GEMM: C = x @ Wqkv for both streams in one launch.
// grid (32, 24): blockIdx.y < 12 -> stream 1, else stream 2.
__global__ __launch_bounds__(256) void gemm_qkv(
    const short* __restrict__ xb1, const short* __restrict__ xb2,
    const short* __restrict__ W1t, const short* __restrict__ W2t,
    short* __restrict__ QK1, short* __restrict__ QK2,
    short* __restrict__ Vt1, short* __restrict__ Vt2) {
  __shared__ short As[128 * 64];
  __shared__ short Bs[128 * 64];
  const int tid = threadIdx.x;
  const int w = tid >> 6, l = tid & 63;
  const int sid = blockIdx.y >= 12;
  const short* A = sid ? xb2 : xb1;
  const short* Bt = sid ? W2t : W1t;
  short* C0 = sid ? QK2 : QK1;
  short* C1 = sid ? Vt2 : Vt1;
  const int m0 = blockIdx.x * 128;
  const int n0 = (sid ? blockIdx.y - 12 : blockIdx.y) * 128;
  const int mi = (w >> 1) * 64, ni = (w & 1) * 64;
  const int lrow = l & 15, lk8 = (l >> 4) * 8;
  const int K = 512;

  f32x4 acc[4][4] = {};

  for (int k0 = 0; k0 < K; k0 += 64) {
    for (int g = 0; g < 4; ++g) {
      int c = g * 256 + w * 64 + l;
      int row = c >> 3, c8 = (c & 7) * 8;
      int ldsoff = (g * 256 + w * 64) * 8;
      gld_lds16(A + (size_t)(m0 + row) * K + k0 + c8, (void*)(As + ldsoff));
      gld_lds16(Bt + (size_t)(n0 + row) * K + k0 + c8, (void*)(Bs + ldsoff));
    }
    __syncthreads();
    __builtin_amdgcn_s_setprio(1);
    for (int kp = 0; kp < 2; ++kp) {
      bf16x8 af[4], bfr[4];
      for (int mf = 0; mf < 4; ++mf)
        af[mf] = *(const bf16x8*)&As[(mi + mf * 16 + lrow) * 64 + kp * 32 + lk8];
      for (int nf = 0; nf < 4; ++nf)
        bfr[nf] = *(const bf16x8*)&Bs[(ni + nf * 16 + lrow) * 64 + kp * 32 + lk8];
      for (int mf = 0; mf < 4; ++mf)
        for (int nf = 0; nf < 4; ++nf)
          acc[mf][nf] = MFMA(af[mf], bfr[nf], acc[mf][nf]);
    }
    __builtin_amdgcn_s_setprio(0);
    __syncthreads();
  }

  for (int mf = 0; mf < 4; ++mf)
    for (int nf = 0; nf < 4; ++nf) {
      int colb = n0 + ni + nf * 16 + lrow;
      int rowb = m0 + mi + mf * 16 + (l >> 4) * 4;
      if (colb < 1024) {
        for (int r = 0; r < 4; ++r)
          C0[(size_t)(rowb + r) * 1024 + colb] = f2bf(acc[mf][nf][r]);
      } else {
        int bb = rowb >> 11, n = rowb & 2047;
        int cv = colb - 1024, hh = cv >> 6, d = cv & 63;
        s16x4 ov;
        ov.x = f2bf(acc[mf][nf][0]);
        ov.y = f2bf(acc[mf][nf][1]);
        ov.z = f2bf(acc[mf][nf][2]);
        ov.w = f2bf(acc[mf][nf][3]);
        *(s16x4*)&C1[(((size_t)(bb * 8 + hh) * 64 + d) << 11) + n] = ov;
      }
    }
}

// ---------------------------------------------------------------------------
// Output-projection GEMM, 64x64 tile (1024 blocks -> 4+ blocks/CU):
// Cf[8192,512] = A[8192,512] @ Wot[512,512]^T + bias
__global__ __launch_bounds__(256) void gemm_out(const short* __restrict__ A,
                                                const short* __restrict__ Bt,
                                                float* __restrict__ Cf,
                                                const float* __restrict__ bias) {
  __shared__ short As[64 * 64];
  __shared__ short Bs[64 * 64];
  const int tid = threadIdx.x;
  const int w = tid >> 6, l = tid & 63;
  const int m0 = blockIdx.x * 64, n0 = blockIdx.y * 64;
  const int mi = (w >> 1) * 32, ni = (w & 1) * 32;
  const int lrow = l & 15, lk8 = (l >> 4) * 8;
  const int K = 512, N = 512;

  f32x4 acc[2][2] = {};

  for (int k0 = 0; k0 < K; k0 += 64) {
    for (int g = 0; g < 2; ++g) {
      int c = g * 256 + tid;
      int row = c >> 3, c8 = (c & 7) * 8;
      gld_lds16(A + (size_t)(m0 + row) * K + k0 + c8, (void*)(As + c * 8));
      gld_lds16(Bt + (size_t)(n0 + row) * K + k0 + c8, (void*)(Bs + c * 8));
    }
    __syncthreads();
    __builtin_amdgcn_s_setprio(1);
    for (int kp = 0; kp < 2; ++kp) {
      bf16x8 af[2], bfr[2];
      for (int mf = 0; mf < 2; ++mf)
        af[mf] = *(const bf16x8*)&As[(mi + mf * 16 + lrow) * 64 + kp * 32 + lk8];
      for (int nf = 0; nf < 2; ++nf)
        bfr[nf] = *(const bf16x8*)&Bs[(ni + nf * 16 + lrow) * 64 + kp * 32 + lk8];
      for (int mf = 0; mf < 2; ++mf)
        for (int nf = 0; nf < 2; ++nf)
          acc[mf][nf] = MFMA(af[mf], bfr[nf], acc[mf][nf]);
    }
    __builtin_amdgcn_s_setprio(0);
    __syncthreads();
  }

  for (int mf = 0; mf < 2; ++mf)
    for (int nf = 0; nf < 2; ++nf)
      for (int r = 0; r < 4; ++r) {
        int row = m0 + mi + mf * 16 + (l >> 4) * 4 + r;
        int col = n0 + ni + nf * 16 + lrow;
        Cf[(size_t)row * N + col] = acc[mf][nf][r] + bias[col];
      }
}

// ---------------------------------------------------------------------------
// Dual-stream flash attention, v9r3 (R18 measured-best, chain changes
// reverted): mfma_32x32x16, kv-split across wave pairs, in-register P via
// permuted-K, counted vmcnt(8), 2 barriers/iter, raw-exp2 softmax, XCD-aware
// block swizzle (each XCD owns 2 bh -> K/V L2-resident, FETCH 69.7->12.3MB).
__global__ __launch_bounds__(256, 2) void attn_kernel(
    const short* __restrict__ QK1, const short* __restrict__ QK2,
    const short* __restrict__ Vt1, const short* __restrict__ Vt2,
    short* __restrict__ Ocat) {
  __shared__ short lds[32768];  // 64KB: K1[2][4096] K2 V1 V2 (shorts)
  short* K1s = lds;
  short* K2s = lds + 8192;
  short* V1s = lds + 16384;
  short* V2s = lds + 24576;

  const int tid = threadIdx.x;
  const int w = tid >> 6, l = tid & 63;
  const int wq = w & 1, wk = w >> 1;
  const int lq = l & 31, hi = l >> 5;
  // XCD swizzle (bijective): same-xcd blocks share 2 bh values
  const int flat = blockIdx.y * 32 + blockIdx.x;
  const int slot = flat >> 3;
  const int bh = ((flat & 7) << 1) + (slot >> 5);
  const int qb = slot & 31;
  const int b = bh >> 3, h = bh & 7;

  const short* Q1p = QK1 + (size_t)b * 2048 * 1024 + h * 64;
  const short* K1p = Q1p + 512;
  const short* Q2p = QK2 + (size_t)b * 2048 * 1024 + h * 64;
  const short* K2p = Q2p + 512;
  const short* V1p = Vt1 + (size_t)bh * 64 * 2048;
  const short* V2p = Vt2 + (size_t)bh * 64 * 2048;

  // Q fragments: lane holds Q[q=lq][d = 16*ck + 8*hi + j], j=0..8
  const int qrow = qb * 64 + wq * 32 + lq;
  bf16x8 q1f[4], q2f[4];
#pragma unroll
  for (int ck = 0; ck < 4; ++ck) {
    q1f[ck] = *(const bf16x8*)&Q1p[(size_t)qrow * 1024 + ck * 16 + hi * 8];
    q2f[ck] = *(const bf16x8*)&Q2p[(size_t)qrow * 1024 + ck * 16 + hi * 8];
  }

  // O^T accumulators: o*a = d 0..31 tile, o*b = d 32..63; col = q = lq
  f32x16 o1a = {}, o1b = {}, o2a = {}, o2b = {};
  float mrun = -1e30f, lrun = 0.f;

  auto stage = [&](int buf, int kt) {
    const int kv0 = kt * 64;
#pragma unroll
    for (int gg = 0; gg < 2; ++gg) {
      int cl = gg * 256 + tid;
      int row = cl >> 3;
      int lc = (cl & 7) ^ (row & 7);  // bank-conflict XOR swizzle (rule 21)
      int lr = row & 31;
      // pi-permuted K row within each 32-row half
      int krow = kv0 + ((row >> 5) << 5) + (((lr >> 3) & 1) << 4) +
                 (((lr >> 2) & 1) << 3) + (((lr >> 4) & 1) << 2) + (lr & 3);
      int doff = buf * 4096 + cl * 8;
      gld_lds16(K1p + (size_t)krow * 1024 + lc * 8, (void*)(K1s + doff));
      gld_lds16(K2p + (size_t)krow * 1024 + lc * 8, (void*)(K2s + doff));
      gld_lds16(V1p + (size_t)row * 2048 + kv0 + lc * 8, (void*)(V1s + doff));
      gld_lds16(V2p + (size_t)row * 2048 + kv0 + lc * 8, (void*)(V2s + doff));
    }
  };
  auto swo = [&](int row, int kc) { return row * 64 + ((kc ^ (row & 7)) * 8); };

  int cur = 0;
  stage(0, 0);

  for (int kt = 0; kt < 32; ++kt) {
    if (kt + 1 < 32) {
      stage(cur ^ 1, kt + 1);  // 8 loads stay in flight across the iter
      asm volatile("s_waitcnt vmcnt(8)" ::: "memory");  // tile t complete
    } else {
      asm volatile("s_waitcnt vmcnt(0)" ::: "memory");
    }
    __builtin_amdgcn_s_barrier();

    // S^T[32 kv][32 q] (log2 domain) for this wave's kv-half, both streams
    const int krd = 32 * wk + lq;
    f32x16 s = {};
    __builtin_amdgcn_s_setprio(1);
#pragma unroll
    for (int ck = 0; ck < 4; ++ck) {
      bf16x8 k1 = *(const bf16x8*)&K1s[cur * 4096 + swo(krd, 2 * ck + hi)];
      bf16x8 k2 = *(const bf16x8*)&K2s[cur * 4096 + swo(krd, 2 * ck + hi)];
      s = MFMA32(k1, q1f[ck], s);
      s = MFMA32(k2, q2f[ck], s);
    }
    __builtin_amdgcn_s_setprio(0);

    // online softmax over lane's 16 kv values (partner l^32 has other 16)
    float mx = s[0];
#pragma unroll
    for (int i = 1; i < 16; ++i) mx = fmaxf(mx, s[i]);
    if (!__all(mx - mrun <= THR2)) {  // defer-max: rarely fires
      float rm = fmaxf(mx, __shfl_xor(mx, 32));
      float newm = fmaxf(mrun, rm);
      float corr = EXP2(mrun - newm);
      mrun = newm;
      lrun *= corr;
#pragma unroll
      for (int i = 0; i < 16; ++i) {
        o1a[i] *= corr; o1b[i] *= corr; o2a[i] *= corr; o2b[i] *= corr;
      }
    }
    float p[16];
#pragma unroll
    for (int i = 0; i < 16; ++i) { p[i] = EXP2(s[i] - mrun); lrun += p[i]; }

    // P register-local repack: pb[c][j] = p[(j&3) + 4c + 8*(j>>2)]
    __hip_bfloat162 a0 = __float22bfloat162_rn(float2{p[0], p[1]});
    __hip_bfloat162 a1 = __float22bfloat162_rn(float2{p[2], p[3]});
    __hip_bfloat162 a2 = __float22bfloat162_rn(float2{p[8], p[9]});
    __hip_bfloat162 a3 = __float22bfloat162_rn(float2{p[10], p[11]});
    __hip_bfloat162 b0 = __float22bfloat162_rn(float2{p[4], p[5]});
    __hip_bfloat162 b1 = __float22bfloat162_rn(float2{p[6], p[7]});
    __hip_bfloat162 b2 = __float22bfloat162_rn(float2{p[12], p[13]});
    __hip_bfloat162 b3 = __float22bfloat162_rn(float2{p[14], p[15]});
    i32x4 w0 = {*(int*)&a0, *(int*)&a1, *(int*)&a2, *(int*)&a3};
    i32x4 w1 = {*(int*)&b0, *(int*)&b1, *(int*)&b2, *(int*)&b3};
    bf16x8 pb0 = *(bf16x8*)&w0, pb1 = *(bf16x8*)&w1;

    // PV: O^T += V^T P^T over this wave's kv-half
    __builtin_amdgcn_s_setprio(1);
#pragma unroll
    for (int c = 0; c < 2; ++c) {
      bf16x8 pb = c ? pb1 : pb0;
      int kcv = 4 * wk + 2 * c + hi;
      bf16x8 v1a = *(const bf16x8*)&V1s[cur * 4096 + swo(lq, kcv)];
      bf16x8 v1b = *(const bf16x8*)&V1s[cur * 4096 + swo(32 + lq, kcv)];
      bf16x8 v2a = *(const bf16x8*)&V2s[cur * 4096 + swo(lq, kcv)];
      bf16x8 v2b = *(const bf16x8*)&V2s[cur * 4096 + swo(32 + lq, kcv)];
      o1a = MFMA32(v1a, pb, o1a);
      o1b = MFMA32(v1b, pb, o1b);
      o2a = MFMA32(v2a, pb, o2a);
      o2b = MFMA32(v2b, pb, o2b);
    }
    __builtin_amdgcn_s_setprio(0);

    asm volatile("s_waitcnt lgkmcnt(0)" ::: "memory");
    __builtin_amdgcn_s_barrier();
    cur ^= 1;
  }

  // ---- cross-wk merge: exact combine of the two kv-half partials ----
  lrun += __shfl_xor(lrun, 32);  // per-q total for this wave's half
  float* cb = (float*)lds;
  float* rg = cb + wq * 4224;  // per-wq region: 4096 O + 64 m + 64 l floats
  if (wk == 1) {
#pragma unroll
    for (int i = 0; i < 16; ++i) {
      rg[i * 64 + l] = o1a[i];
      rg[(16 + i) * 64 + l] = o1b[i];
      rg[(32 + i) * 64 + l] = o2a[i];
      rg[(48 + i) * 64 + l] = o2b[i];
    }
    rg[4096 + l] = mrun;
    rg[4160 + l] = lrun;
  }
  __syncthreads();
  if (wk == 0) {
    float m1 = rg[4096 + l], l1 = rg[4160 + l];
    float mstar = fmaxf(mrun, m1);
    float e0 = EXP2(mrun - mstar), e1 = EXP2(m1 - mstar);
    float inv = 1.0f / (lrun * e0 + l1 * e1);
    float av0 = e0 * inv, av1 = e1 * inv;
#pragma unroll
    for (int i = 0; i < 16; ++i) {
      o1a[i] = o1a[i] * av0 + rg[i * 64 + l] * av1;
      o1b[i] = o1b[i] * av0 + rg[(16 + i) * 64 + l] * av1;
      o2a[i] = o2a[i] * av0 + rg[(32 + i) * 64 + l] * av1;
      o2b[i] = o2b[i] * av0 + rg[(48 + i) * 64 + l] * av1;
    }
    // write: lane's d rows = 8*rq + 4*hi + e (+32 for *b tiles), q = lq
    const size_t base1 = ((size_t)b * 4096 + qrow) * 512 + h * 64;
    const size_t base2 = base1 + (size_t)2048 * 512;
#pragma unroll
    for (int rq = 0; rq < 4; ++rq) {
      int d0 = 8 * rq + 4 * hi;
      s16x4 ov;
      ov.x = f2bf(o1a[rq * 4 + 0]); ov.y = f2bf(o1a[rq * 4 + 1]);
      ov.z = f2bf(o1a[rq * 4 + 2]); ov.w = f2bf(o1a[rq * 4 + 3]);
      *(s16x4*)&Ocat[base1 + d0] = ov;
      ov.x = f2bf(o1b[rq * 4 + 0]); ov.y = f2bf(o1b[rq * 4 + 1]);
      ov.z = f2bf(o1b[rq * 4 + 2]); ov.w = f2bf(o1b[rq * 4 + 3]);
      *(s16x4*)&Ocat[base1 + 32 + d0] = ov;
      ov.x = f2bf(o2a[rq * 4 + 0]); ov.y = f2bf(o2a[rq * 4 + 1]);
      ov.z = f2bf(o2a[rq * 4 + 2]); ov.w = f2bf(o2a[rq * 4 + 3]);
      *(s16x4*)&Ocat[base2 + d0] = ov;
      ov.x = f2bf(o2b[rq * 4 + 0]); ov.y = f2bf(o2b[rq * 4 + 1]);
      ov.z = f2bf(o2b[rq * 4 + 2]); ov.w = f2bf(o2b[rq * 4 + 3]);
      *(s16x4*)&Ocat[base2 + 32 + d0] = ov;
    }
  }
}

// ---------------------------------------------------------------------------
extern "C" void kernel_launch(void* const* d_in, const int* in_sizes, int n_in,
                              void* d_out, int out_size, void* d_ws,
                              size_t ws_size, hipStream_t stream) {
  const float* x1 = (const float*)d_in[0];
  const float* x2 = (const float*)d_in[1];
  const float* Wq1 = (const float*)d_in[2];
  const float* Wq2 = (const float*)d_in[3];
  const float* Wo = (const float*)d_in[4];
  const float* bo = (const float*)d_in[5];
  float* out = (float*)d_out;

  // workspace layout (bf16 elements); total ~45.6 MB
  short* p = (short*)d_ws;
  short* xb1 = p;  p += (size_t)4096 * 512;
  short* xb2 = p;  p += (size_t)4096 * 512;
  short* W1t = p;  p += (size_t)1536 * 512;
  short* W2t = p;  p += (size_t)1536 * 512;
  short* Wot = p;  p += (size_t)512 * 512;
  short* QK1 = p;  p += (size_t)4096 * 1024;
  short* QK2 = p;  p += (size_t)4096 * 1024;
  short* Vt1 = p;  p += (size_t)2 * 8 * 64 * 2048;
  short* Vt2 = p;  p += (size_t)2 * 8 * 64 * 2048;
  short* Ocat = p; p += (size_t)8192 * 512;

  preprocess<<<4544, 256, 0, stream>>>(x1, x2, Wq1, Wq2, Wo, xb1, xb2, W1t,
                                       W2t, Wot);

  gemm_qkv<<<dim3(32, 24), 256, 0, stream>>>(xb1, xb2, W1t, W2t, QK1, QK2,
                                             Vt1, Vt2);

  attn_kernel<<<dim3(32, 16), 256, 0, stream>>>(QK1, QK2, Vt1, Vt2, Ocat);

  gemm_out<<<dim3(128, 8), 256, 0, stream>>>(Ocat, Wot, out, bo);
}